// Round 13
// baseline (15.228 us; speedup 1.0000x reference)
//
#include <hip/hip_runtime.h>
#include <hip/hip_bf16.h>
#include <math.h>

// R12: R11's 2-node in-block-merge structure, with BARRIER-FREE wave-local
// staging. Each of the 4 waves owns one 512-target quarter: it packs ONLY its
// own quarter into its own LDS region (no __syncthreads before the main
// loop), so waves desynchronize and pack-VALU overlaps sibling waves' MFMA.
// K-half-1 fragments stored as short4 (ds_read_b64), LDS 64->48 KB.
// MFMA packing (R7/R8/R10/R11-validated, absmax ~0):
//   A row r (target): k0-7 = [th,th,tl.xy] | k8-15 = [tl.z,qh,ql,0..]
//   B col c (pred)  : k0-7 = [-ph,-pl,-ph.xy] | k8-15 = [-ph.z,1,1,0..]
//   dot = 0.5*t^2 - p.t;  d^2/2 = dot + 0.5*p^2 (epilogue).

typedef short short8 __attribute__((ext_vector_type(8)));
typedef short short4v __attribute__((ext_vector_type(4)));
typedef float f32x16 __attribute__((ext_vector_type(16)));

__device__ __forceinline__ unsigned short f2bf(float f) {  // RNE f32->bf16
  unsigned u = __float_as_uint(f);
  u = u + 0x7FFFu + ((u >> 16) & 1u);
  return (unsigned short)(u >> 16);
}
__device__ __forceinline__ float bf2f(unsigned short h) {
  return __uint_as_float(((unsigned)h) << 16);
}

#define TPB 256
#define NPTS 2048

__global__ __launch_bounds__(TPB, 2) void chamfer_main_kernel(
    const float* __restrict__ pred, const float* __restrict__ targ,
    const float* __restrict__ sym_flag, float* __restrict__ partial,
    int N, int B, int panelsPerBatch) {
  __shared__ short8 sA0[NPTS];    // 32 KB: K-half-0 fragments
  __shared__ short4v sA1[NPTS];   // 16 KB: K-half-1 fragments
  __shared__ float sm[4][64];     // per-quarter col mins

  const int blk = blockIdx.x;
  const int pp = blk % panelsPerBatch;  // 64-pred panel (32 per batch)
  const int b = blk / panelsPerBatch;

  const int lane = threadIdx.x & 63;
  const int w = threadIdx.x >> 6;  // wave = target quarter 0..3
  const int g = lane >> 5;         // K-half this lane supplies to MFMA
  const int l31 = lane & 31;
  const int colBase = pp * 64;

  // ---- B fragments for BOTH 32-pred tiles (negated hi/lo split)
  short8 bf0, bf1;
#pragma unroll
  for (int pt = 0; pt < 2; ++pt) {
    const int col = colBase + pt * 32 + l31;
    const float* pq = pred + ((size_t)b * N + col) * 3;
    const float x = pq[0], y = pq[1], z = pq[2];
    const unsigned short hx = f2bf(-x), hy = f2bf(-y), hz = f2bf(-z);
    const unsigned short lx = f2bf(-x - bf2f(hx));
    const unsigned short ly = f2bf(-y - bf2f(hy));
    const unsigned short lz = f2bf(-z - bf2f(hz));
    short8 r;
    if (g == 0)
      r = short8{(short)hx, (short)hy, (short)hz, (short)lx,
                 (short)ly, (short)lz, (short)hx, (short)hy};
    else
      r = short8{(short)hz, (short)0x3F80, (short)0x3F80, 0, 0, 0, 0, 0};
    if (pt == 0) bf0 = r; else bf1 = r;
  }

  // ---- WAVE-LOCAL staging: this wave packs its own 512-target quarter.
  // Lane owns 8 CONTIGUOUS targets -> 6 coalesced float4 loads.
  {
    const int t0 = w * 512 + lane * 8;
    const float4* tg4 = (const float4*)(targ + ((size_t)b * N + t0) * 3);
    float tf[24];
#pragma unroll
    for (int k = 0; k < 6; ++k) {
      const float4 v = tg4[k];
      tf[4 * k] = v.x; tf[4 * k + 1] = v.y;
      tf[4 * k + 2] = v.z; tf[4 * k + 3] = v.w;
    }
#pragma unroll
    for (int j = 0; j < 8; ++j) {
      const float x = tf[3 * j], y = tf[3 * j + 1], z = tf[3 * j + 2];
      const unsigned short thx = f2bf(x), thy = f2bf(y), thz = f2bf(z);
      const unsigned short tlx = f2bf(x - bf2f(thx));
      const unsigned short tly = f2bf(y - bf2f(thy));
      const unsigned short tlz = f2bf(z - bf2f(thz));
      const float q = 0.5f * fmaf(z, z, fmaf(y, y, x * x));
      const unsigned short qh = f2bf(q), ql = f2bf(q - bf2f(qh));
      sA0[t0 + j] = short8{(short)thx, (short)thy, (short)thz, (short)thx,
                           (short)thy, (short)thz, (short)tlx, (short)tly};
      sA1[t0 + j] = short4v{(short)tlz, (short)qh, (short)ql, 0};
    }
  }
  // NO __syncthreads: each wave reads only the region it wrote (compiler
  // orders the wave's own ds_write -> ds_read via lgkmcnt).

  const f32x16 zc = {0.f, 0.f, 0.f, 0.f, 0.f, 0.f, 0.f, 0.f,
                     0.f, 0.f, 0.f, 0.f, 0.f, 0.f, 0.f, 0.f};
  float rm0[8], rm1[8];
#pragma unroll
  for (int i = 0; i < 8; ++i) { rm0[i] = 3.4e38f; rm1[i] = 3.4e38f; }

  // ---- this wave's quarter: 16 x (ds_read + 2 indep MFMA + 16 min3)
#pragma unroll 4
  for (int ta = 0; ta < 16; ++ta) {
    const int idx = w * 512 + ta * 32 + l31;
    short8 a;
    if (g == 0) {
      a = sA0[idx];
    } else {
      const short4v v = sA1[idx];
      a = short8{v.x, v.y, v.z, v.w, 0, 0, 0, 0};
    }
    const f32x16 d0 = __builtin_amdgcn_mfma_f32_32x32x16_bf16(a, bf0, zc, 0, 0, 0);
    const f32x16 d1 = __builtin_amdgcn_mfma_f32_32x32x16_bf16(a, bf1, zc, 0, 0, 0);
#pragma unroll
    for (int i = 0; i < 8; ++i) {
      rm0[i] = fminf(rm0[i], fminf(d0[2 * i], d0[2 * i + 1]));  // v_min3
      rm1[i] = fminf(rm1[i], fminf(d1[2 * i], d1[2 * i + 1]));
    }
  }

  // ---- per-col min for this quarter -> LDS
  float m0 = rm0[0], m1 = rm1[0];
#pragma unroll
  for (int i = 1; i < 8; ++i) { m0 = fminf(m0, rm0[i]); m1 = fminf(m1, rm1[i]); }
  m0 = fminf(m0, __shfl_xor(m0, 32));  // merge K-half rows (lane^32)
  m1 = fminf(m1, __shfl_xor(m1, 32));
  if (lane < 32) {
    sm[w][l31] = m0;
    sm[w][32 + l31] = m1;
  }
  __syncthreads();  // the ONLY block barrier: quarter merge

  // ---- epilogue: threads 0..63 own the panel's 64 preds
  if (threadIdx.x < 64) {
    const int i = threadIdx.x;
    const float mm = fminf(fminf(sm[0][i], sm[1][i]), fminf(sm[2][i], sm[3][i]));
    const size_t gc = (size_t)b * N + colBase + i;
    const float x = pred[gc * 3], y = pred[gc * 3 + 1], z = pred[gc * 3 + 2];
    const float tx = targ[gc * 3], ty = targ[gc * 3 + 1], tz = targ[gc * 3 + 2];
    const float hp2 = 0.5f * (x * x + y * y + z * z);
    const float dsym = sqrtf(fmaxf(2.f * (mm + hp2), 1e-12f));
    const float dx = x - tx, dy = y - ty, dz = z - tz;
    const float dasym = sqrtf(dx * dx + dy * dy + dz * dz);
    const float f = sym_flag[b];
    float c = f * dsym + (1.f - f) * dasym;
#pragma unroll
    for (int off = 32; off > 0; off >>= 1) c += __shfl_xor(c, off);
    if (i == 0) partial[blk] = c;  // plain store, deterministic
  }
}

// k2: one block, fixed-order sum of 512 partials.
__global__ __launch_bounds__(256) void chamfer_sum_kernel(
    const float* __restrict__ partial, float* __restrict__ out, float invNB) {
  const int t = threadIdx.x;
  float s = partial[t] + partial[t + 256];
#pragma unroll
  for (int off = 32; off > 0; off >>= 1) s += __shfl_xor(s, off);
  __shared__ float sW[4];
  if ((t & 63) == 0) sW[t >> 6] = s;
  __syncthreads();
  if (t == 0) out[0] = (sW[0] + sW[1] + sW[2] + sW[3]) * invNB;
}

extern "C" void kernel_launch(void* const* d_in, const int* in_sizes, int n_in,
                              void* d_out, int out_size, void* d_ws, size_t ws_size,
                              hipStream_t stream) {
  const float* pred = (const float*)d_in[0];
  const float* targ = (const float*)d_in[1];
  const float* sym_flag = (const float*)d_in[2];
  float* out = (float*)d_out;

  const int B = in_sizes[2];            // 16
  const int N = in_sizes[0] / (B * 3);  // 2048 (kernels sized for this)

  const int panelsPerBatch = N / 64;    // 32
  const int grid = B * panelsPerBatch;  // 512
  float* partial = (float*)d_ws;        // 512 floats

  chamfer_main_kernel<<<grid, TPB, 0, stream>>>(pred, targ, sym_flag, partial,
                                                N, B, panelsPerBatch);
  chamfer_sum_kernel<<<1, 256, 0, stream>>>(partial, out,
                                            1.0f / (float)(N * B));
}